// Round 6
// baseline (73.896 us; speedup 1.0000x reference)
//
#include <hip/hip_runtime.h>
#include <math.h>

// MeshfreeKAN2D forward.
// x:[B,2] nodes:[N,2] W1a:[16,7] W1b:[16,7] W2:[1,112] w:[N,1] -> out:[B,1]
// B=1024, N=2048 in this instance.
//
// One block handles QPB=4 query rows (grid = 256 = 1 block/CU, single round):
//   Phase 1: one pass over nodes; each node tested against all 4 queries;
//            hits ((q,n) pairs, ~64/query) compacted into ONE LDS list.
//   Phase 2: KAN eval over ~256 compacted hits with ~full lane utilization;
//            per-query sums via LDS float atomics (~256 ops total).
//   Orphan fallback (zero in-support nodes; prob ~e^-64): serial exact 8-NN
//            per orphan query, matching lax.top_k tie semantics (low index).

constexpr int NB    = 7;
constexpr int NH    = 16;
constexpr int BLOCK = 256;
constexpr int QPB   = 4;     // queries per block
constexpr int CAP   = 4096;  // hit-list capacity (practical max ~400/block)

__global__ __launch_bounds__(BLOCK) void meshfree_kan_fwd(
    const float* __restrict__ x,
    const float* __restrict__ nodes,
    const float* __restrict__ W1a,
    const float* __restrict__ W1b,
    const float* __restrict__ W2,
    const float* __restrict__ w,
    float* __restrict__ out,
    int B, int N)
{
    __shared__ float sW1a[NH * NB];
    __shared__ float sW1b[NH * NB];
    __shared__ float sW2 [NH * NB];
    __shared__ int   slist[CAP];
    __shared__ int   hcount;
    __shared__ float sacc[QPB][2];   // per-query {sum_phi, sum_phi*w}
    __shared__ float sx[QPB][2];

    const int tid   = threadIdx.x;
    const int qbase = blockIdx.x * QPB;

    for (int i = tid; i < NH * NB; i += BLOCK) {
        sW1a[i] = W1a[i];
        sW1b[i] = W1b[i];
        sW2[i]  = W2[i];
    }
    if (tid == 0) hcount = 0;
    if (tid < QPB) {
        sacc[tid][0] = 0.0f;
        sacc[tid][1] = 0.0f;
        const int b = qbase + tid;
        if (b < B) {
            sx[tid][0] = x[2 * b + 0];
            sx[tid][1] = x[2 * b + 1];
        }
    }
    __syncthreads();

    const int nq = min(QPB, B - qbase);

    // ---------- phase 1: fused distance pass + hit compaction ----------
    for (int base = 0; base < N; base += BLOCK) {
        const int n = base + tid;
        if (n < N) {
            const float2 nd = ((const float2*)nodes)[n];
            #pragma unroll
            for (int q = 0; q < QPB; ++q) {
                if (q < nq) {
                    const float dx = sx[q][0] - nd.x;
                    const float dy = sx[q][1] - nd.y;
                    const float d2 = dx * dx + dy * dy;
                    // dist <= 0.1  <=>  d2 <= 0.01 (+ inclusive fuzz; boundary
                    // terms carry window ~(1-q)^3 ~ 1e-21 — negligible)
                    if (d2 <= 0.0100000019f) {
                        const int p = atomicAdd(&hcount, 1);
                        if (p < CAP) slist[p] = (q << 16) | n;
                    }
                }
            }
        }
    }
    __syncthreads();
    const int H = min(hcount, CAP);  // clamp is memory-safety only; CAP is
                                     // ~10x the practical worst case

    // ---------- phase 2: KAN eval over compacted hits ----------
    for (int k = tid; k < H; k += BLOCK) {
        const int e = slist[k];
        const int q = e >> 16;
        const int n = e & 0xffff;
        const float2 nd = ((const float2*)nodes)[n];
        const float dx = sx[q][0] - nd.x;
        const float dy = sx[q][1] - nd.y;
        const float dist = sqrtf(dx * dx + dy * dy);
        const float qq = dist * 10.0f;   // dist / 0.1
        const float kx = dx * 10.0f;
        const float ky = dy * 10.0f;

        // input-layer basis as 2-point lerp; |kx|,|ky| <= 1+ulp -> j in [1,5]
        const float u0 = (kx + 1.5f) * 2.0f;
        const float f0 = floorf(u0);
        const int   j0 = (int)f0;
        const float t0 = u0 - f0;
        const float u1 = (ky + 1.5f) * 2.0f;
        const float f1 = floorf(u1);
        const int   j1 = (int)f1;
        const float t1 = u1 - f1;

        float acc = 0.0f;
        #pragma unroll
        for (int h = 0; h < NH; ++h) {
            const float hid =
                sW1a[h * NB + j0]     * (1.0f - t0) +
                sW1a[h * NB + j0 + 1] * t0 +
                sW1b[h * NB + j1]     * (1.0f - t1) +
                sW1b[h * NB + j1 + 1] * t1;
            const float uh = (hid + 1.5f) * 2.0f;
            const float fh = floorf(uh);
            const int   jh = (int)fh;
            const float th = uh - fh;
            const float c0 = ((unsigned)jh       <= 6u) ? sW2[h * NB + jh]     : 0.0f;
            const float c1 = ((unsigned)(jh + 1) <= 6u) ? sW2[h * NB + jh + 1] : 0.0f;
            acc += c0 * (1.0f - th) + c1 * th;
        }

        // stable softplus
        const float phi_raw = fmaxf(acc, 0.0f) + log1pf(expf(-fabsf(acc)));
        // cubic window
        float wnd;
        if (qq <= 0.5f) {
            wnd = 2.0f / 3.0f - 4.0f * qq * qq + 4.0f * qq * qq * qq;
        } else if (qq <= 1.0f) {
            wnd = 4.0f / 3.0f - 4.0f * qq + 4.0f * qq * qq
                  - (4.0f / 3.0f) * qq * qq * qq;
        } else {
            wnd = 0.0f;
        }
        const float phi = phi_raw * wnd;
        atomicAdd(&sacc[q][0], phi);
        atomicAdd(&sacc[q][1], phi * w[n]);
    }
    __syncthreads();

    // ---------- finalize: one thread per query ----------
    if (tid < nq) {
        const int b = qbase + tid;
        const float ps = sacc[tid][0];
        float result;
        if (fabsf(ps) >= 1e-14f) {
            result = sacc[tid][1] / (ps + 1e-12f);
        } else {
            // orphan fallback: exact serial 8-NN (d^2 selection; strict <
            // gives lowest-index ties, matching lax.top_k)
            const float qx = sx[tid][0];
            const float qy = sx[tid][1];
            float dsel[8];
            int   isel[8];
            #pragma unroll 1
            for (int k = 0; k < 8; ++k) {
                float md = INFINITY;
                int   mi = 0;
                for (int n = 0; n < N; ++n) {
                    const float2 nd = ((const float2*)nodes)[n];
                    const float dx = qx - nd.x;
                    const float dy = qy - nd.y;
                    float d2 = dx * dx + dy * dy;
                    bool seen = false;
                    #pragma unroll
                    for (int j = 0; j < 8; ++j)
                        if (j < k && isel[j] == n) seen = true;
                    if (!seen && d2 < md) { md = d2; mi = n; }
                }
                dsel[k] = sqrtf(md);
                isel[k] = mi;
            }
            float wts[8];
            float s = 0.0f;
            #pragma unroll
            for (int k = 0; k < 8; ++k) {
                wts[k] = expf(-200.0f * dsel[k]);
                s += wts[k];
            }
            float r = 0.0f;
            #pragma unroll
            for (int k = 0; k < 8; ++k)
                r += (wts[k] / (s + 1e-18f)) * w[isel[k]];
            result = r;
        }
        out[b] = result;
    }
}

extern "C" void kernel_launch(void* const* d_in, const int* in_sizes, int n_in,
                              void* d_out, int out_size, void* d_ws, size_t ws_size,
                              hipStream_t stream) {
    const float* x     = (const float*)d_in[0];
    const float* nodes = (const float*)d_in[1];
    const float* W1a   = (const float*)d_in[2];
    const float* W1b   = (const float*)d_in[3];
    const float* W2    = (const float*)d_in[4];
    const float* w     = (const float*)d_in[5];
    float* out = (float*)d_out;

    const int B = in_sizes[0] / 2;
    const int N = in_sizes[1] / 2;

    const int grid = (B + QPB - 1) / QPB;
    meshfree_kan_fwd<<<grid, BLOCK, 0, stream>>>(x, nodes, W1a, W1b, W2, w,
                                                 out, B, N);
}